// Round 1
// baseline (661.600 us; speedup 1.0000x reference)
//
#include <hip/hip_runtime.h>
#include <hip/hip_bf16.h>

#define N_NODES 100000
#define N_EDGES 3200000
#define F_IN    128
#define HID     16
#define N_DRUGS 2000

// ---------------- degree / dinv ----------------

__global__ void k_deg_init(float* __restrict__ deg) {
    int i = blockIdx.x * blockDim.x + threadIdx.x;
    if (i < N_NODES) deg[i] = 1.0f;  // self-loop
}

__global__ void k_deg_count(const int* __restrict__ dst, float* __restrict__ deg) {
    int e = blockIdx.x * blockDim.x + threadIdx.x;
    if (e < N_EDGES) atomicAdd(&deg[dst[e]], 1.0f);
}

__global__ void k_dinv(float* __restrict__ deg) {
    int i = blockIdx.x * blockDim.x + threadIdx.x;
    if (i < N_NODES) deg[i] = rsqrtf(deg[i]);  // deg >= 1 always
}

// ---------------- hw = x @ W1 (100000x128 @ 128x16) ----------------

__global__ void k_xw1(const float* __restrict__ x, const float* __restrict__ W1,
                      float* __restrict__ hw) {
    __shared__ float xs[16][129];   // +1 pad breaks 4-way bank conflict on xs[r][k]
    __shared__ float ws[128][16];
    int tid = threadIdx.x;  // 256
    for (int i = tid; i < 128 * 16; i += 256) ws[i >> 4][i & 15] = W1[i];
    int row0 = blockIdx.x * 16;
    for (int i = tid; i < 16 * 128; i += 256) {
        int r = i >> 7, c = i & 127;
        int gr = row0 + r;
        xs[r][c] = (gr < N_NODES) ? x[(long)gr * F_IN + c] : 0.0f;
    }
    __syncthreads();
    int h = tid & 15, r = tid >> 4;
    float acc = 0.0f;
#pragma unroll
    for (int k = 0; k < 128; ++k) acc += xs[r][k] * ws[k][h];
    int gr = row0 + r;
    if (gr < N_NODES) hw[gr * HID + h] = acc;
}

// ---------------- agg init: b + dinv^2 * hw (self loop message) ----------------

__global__ void k_agg_init(const float* __restrict__ dinv, const float* __restrict__ hw,
                           const float* __restrict__ b, float* __restrict__ agg) {
    int i = blockIdx.x * blockDim.x + threadIdx.x;
    if (i < N_NODES * HID) {
        int node = i >> 4, f = i & 15;
        float dv = dinv[node];
        agg[i] = b[f] + dv * dv * hw[i];
    }
}

// ---------------- edge scatter: agg[dst] += dinv[src]*dinv[dst]*hw[src] ----------------

__global__ void k_scatter(const int* __restrict__ src, const int* __restrict__ dst,
                          const float* __restrict__ dinv, const float* __restrict__ hw,
                          float* __restrict__ agg) {
    long gid = (long)blockIdx.x * blockDim.x + threadIdx.x;
    if (gid >= (long)N_EDGES * HID) return;
    int f = (int)(gid & 15);
    int e = (int)(gid >> 4);
    int s = src[e], d = dst[e];
    float nrm = dinv[s] * dinv[d];
    atomicAdd(&agg[d * HID + f], nrm * hw[s * HID + f]);
}

// ---------------- hw2 = relu(agg) @ W2 ----------------

__global__ void k_hw2(const float* __restrict__ agg, const float* __restrict__ W2,
                      float* __restrict__ hw2) {
    __shared__ float w2s[16][17];
    int tid = threadIdx.x;  // 256
    w2s[tid >> 4][tid & 15] = W2[tid];
    __syncthreads();
    int gid = blockIdx.x * 256 + tid;
    if (gid >= N_NODES * HID) return;
    int node = gid >> 4, f = gid & 15;
    float acc = 0.0f;
#pragma unroll
    for (int k = 0; k < 16; ++k) {
        float hv = agg[node * HID + k];
        hv = hv > 0.0f ? hv : 0.0f;
        acc += hv * w2s[k][f];
    }
    hw2[gid] = acc;
}

// ---------------- t = hd @ predictor (2000x16 @ 16x16) ----------------

__global__ void k_t(const float* __restrict__ agg, const float* __restrict__ pred,
                    float* __restrict__ t) {
    __shared__ float ps[256];
    int tid = threadIdx.x;
    ps[tid] = pred[tid];
    __syncthreads();
    int gid = blockIdx.x * 256 + tid;
    if (gid >= N_DRUGS * HID) return;
    int i = gid >> 4, k = gid & 15;
    float acc = 0.0f;
#pragma unroll
    for (int m = 0; m < 16; ++m) acc += agg[i * HID + m] * ps[m * 16 + k];
    t[gid] = acc;
}

// ---------------- out[i][j] = dot(t[i], hd[j]) ----------------

__global__ void k_out(const float* __restrict__ t, const float* __restrict__ agg,
                      float* __restrict__ out) {
    __shared__ float ts[16][17], hs[16][17];
    int tid = threadIdx.x;  // 256
    int li = tid >> 4, lj = tid & 15;
    int i0 = blockIdx.y * 16, j0 = blockIdx.x * 16;
    ts[li][lj] = t[(i0 + li) * HID + lj];
    hs[li][lj] = agg[(j0 + li) * HID + lj];
    __syncthreads();
    float acc = 0.0f;
#pragma unroll
    for (int k = 0; k < 16; ++k) acc += ts[li][k] * hs[lj][k];
    out[(long)(i0 + li) * N_DRUGS + (j0 + lj)] = acc;
}

extern "C" void kernel_launch(void* const* d_in, const int* in_sizes, int n_in,
                              void* d_out, int out_size, void* d_ws, size_t ws_size,
                              hipStream_t stream) {
    const float* x    = (const float*)d_in[0];
    const int*   ei   = (const int*)d_in[1];
    const float* W1   = (const float*)d_in[2];
    const float* b1   = (const float*)d_in[3];
    const float* W2   = (const float*)d_in[4];
    const float* b2   = (const float*)d_in[5];
    const float* pred = (const float*)d_in[6];
    float* out = (float*)d_out;

    const int* src = ei;             // edge_index[0]
    const int* dst = ei + N_EDGES;   // edge_index[1]

    float* ws   = (float*)d_ws;
    float* dinv = ws;                          // N_NODES
    float* hw   = ws + N_NODES;                // N_NODES*16  (reused for hw2)
    float* agg  = ws + N_NODES + N_NODES * 16; // N_NODES*16  (reused for layer2)
    float* tbuf = ws + N_NODES + N_NODES * 32; // N_DRUGS*16

    const int B = 256;

    // degree + dinv
    k_deg_init<<<(N_NODES + B - 1) / B, B, 0, stream>>>(dinv);
    k_deg_count<<<(N_EDGES + B - 1) / B, B, 0, stream>>>(dst, dinv);
    k_dinv<<<(N_NODES + B - 1) / B, B, 0, stream>>>(dinv);

    // layer 1
    k_xw1<<<(N_NODES + 15) / 16, B, 0, stream>>>(x, W1, hw);
    k_agg_init<<<(N_NODES * HID + B - 1) / B, B, 0, stream>>>(dinv, hw, b1, agg);
    {
        long total = (long)N_EDGES * HID;
        k_scatter<<<(int)((total + B - 1) / B), B, 0, stream>>>(src, dst, dinv, hw, agg);
    }

    // layer 2: hw2 = relu(agg) @ W2  (hw buffer reused)
    k_hw2<<<(N_NODES * HID + B - 1) / B, B, 0, stream>>>(agg, W2, hw);
    k_agg_init<<<(N_NODES * HID + B - 1) / B, B, 0, stream>>>(dinv, hw, b2, agg);
    {
        long total = (long)N_EDGES * HID;
        k_scatter<<<(int)((total + B - 1) / B), B, 0, stream>>>(src, dst, dinv, hw, agg);
    }

    // readout: t = hd @ P ; out = t @ hd^T
    k_t<<<(N_DRUGS * HID + B - 1) / B, B, 0, stream>>>(agg, pred, tbuf);
    dim3 og(N_DRUGS / 16, N_DRUGS / 16);
    k_out<<<og, B, 0, stream>>>(tbuf, agg, out);
}